// Round 5
// baseline (409.654 us; speedup 1.0000x reference)
//
#include <hip/hip_runtime.h>
#include <math.h>

// z: [32,64,64,64] (B,C,H,W)  N = B*H*W = 131072 locations, C = 64
// E: [512,64]
// out (fp32 flat): loss(1) | z_q(8388608) | perp(1) | enc(67108864) | idx(131072)
#define OUT_ZQ   1LL
#define OUT_PERP 8388609LL
#define OUT_ENC  8388610LL
#define OUT_IDX  75497474LL

// esum scratch lives at the start of the enc region (proven safe in R3:
// written before vq_outputs, fully overwritten by it afterwards).
// ws usage (6 KB, proven): [0..511] hist(int) | [512..1535] loss partials f32
#define WS_HIST  0
#define WS_LOSSP 512

// Setup: esum_j = np.sum(e*e, axis=1) replicated with numpy's exact pairwise
// order for n=64: 8 accumulators striding 8, combined ((r0+r1)+(r2+r3))+((r4+r5)+(r6+r7)).
__global__ void vq_setup(const float* __restrict__ E, float* __restrict__ out,
                         float* __restrict__ ws) {
#pragma clang fp contract(off)
  int j = threadIdx.x; // 512 threads
  const float* e = E + j * 64;
  float r0 = e[0]*e[0], r1 = e[1]*e[1], r2 = e[2]*e[2], r3 = e[3]*e[3];
  float r4 = e[4]*e[4], r5 = e[5]*e[5], r6 = e[6]*e[6], r7 = e[7]*e[7];
#pragma unroll
  for (int i = 8; i < 64; i += 8) {
    r0 += e[i+0]*e[i+0]; r1 += e[i+1]*e[i+1];
    r2 += e[i+2]*e[i+2]; r3 += e[i+3]*e[i+3];
    r4 += e[i+4]*e[i+4]; r5 += e[i+5]*e[i+5];
    r6 += e[i+6]*e[i+6]; r7 += e[i+7]*e[i+7];
  }
  float es = ((r0 + r1) + (r2 + r3)) + ((r4 + r5) + (r6 + r7));
  (out + OUT_ENC)[j] = es;
  ((int*)ws)[WS_HIST + j] = 0;
}

// Argmin replicating the reference's fp32 rounding structure:
//   d_j = fl( fl(zsum + esum_j) - fl(2*mm_j) ),  mm_j = sequential-k fp32 FMA chain
//   zsum = numpy pairwise over fl(z_c^2)
// First-min via strict < over ascending j.
__global__ __launch_bounds__(256) void vq_argmin_np(const float* __restrict__ z,
                                                    const float* __restrict__ E,
                                                    const float* __restrict__ esum,
                                                    float* __restrict__ out) {
#pragma clang fp contract(off)
  const int tid  = threadIdx.x;
  const int lane = tid & 63;
  const int wid  = __builtin_amdgcn_readfirstlane(tid >> 6);
  const int row  = blockIdx.x * 4 + wid;      // 512 blocks -> rows 0..2047
  const int b = row >> 6, h = row & 63;
  const size_t zbase = (size_t)b * 262144 + (size_t)h * 64;

  float zf[64];
#pragma unroll
  for (int c = 0; c < 64; ++c)
    zf[c] = z[zbase + (size_t)c * 4096 + lane];

  // zsum: numpy pairwise (n=64), squares rounded individually (contract off)
  float r0 = zf[0]*zf[0], r1 = zf[1]*zf[1], r2 = zf[2]*zf[2], r3 = zf[3]*zf[3];
  float r4 = zf[4]*zf[4], r5 = zf[5]*zf[5], r6 = zf[6]*zf[6], r7 = zf[7]*zf[7];
#pragma unroll
  for (int i = 8; i < 64; i += 8) {
    r0 += zf[i+0]*zf[i+0]; r1 += zf[i+1]*zf[i+1];
    r2 += zf[i+2]*zf[i+2]; r3 += zf[i+3]*zf[i+3];
    r4 += zf[i+4]*zf[i+4]; r5 += zf[i+5]*zf[i+5];
    r6 += zf[i+6]*zf[i+6]; r7 += zf[i+7]*zf[i+7];
  }
  const float zsum = ((r0 + r1) + (r2 + r3)) + ((r4 + r5) + (r6 + r7));

  float best = 1e30f; int bi = 0;
  for (int j = 0; j < 512; j += 4) {
    const float* __restrict__ e0 = E + (size_t)j * 64;  // wave-uniform -> s_load
    const float* __restrict__ e1 = e0 + 64;
    const float* __restrict__ e2 = e0 + 128;
    const float* __restrict__ e3 = e0 + 192;
    float a0 = 0.f, a1 = 0.f, a2 = 0.f, a3 = 0.f;
#pragma unroll
    for (int c = 0; c < 64; ++c) {       // sequential k-order fused-FMA chain (BLAS-like)
      a0 = fmaf(zf[c], e0[c], a0);
      a1 = fmaf(zf[c], e1[c], a1);
      a2 = fmaf(zf[c], e2[c], a2);
      a3 = fmaf(zf[c], e3[c], a3);
    }
    float d0 = (zsum + esum[j + 0]) - 2.0f * a0;
    float d1 = (zsum + esum[j + 1]) - 2.0f * a1;
    float d2 = (zsum + esum[j + 2]) - 2.0f * a2;
    float d3 = (zsum + esum[j + 3]) - 2.0f * a3;
    if (d0 < best) { best = d0; bi = j;     }
    if (d1 < best) { best = d1; bi = j + 1; }
    if (d2 < best) { best = d2; bi = j + 2; }
    if (d3 < best) { best = d3; bi = j + 3; }
  }
  out[OUT_IDX + (size_t)row * 64 + lane] = (float)bi;
}

// one-hot, z_q, loss partials, histogram — from final idx. (Unchanged: passed.)
__global__ __launch_bounds__(256) void vq_outputs(const float* __restrict__ z,
                                                  const float* __restrict__ E,
                                                  float* __restrict__ ws,
                                                  float* __restrict__ out) {
  const int tid  = threadIdx.x;
  const int lane = tid & 63;
  const int waveu = __builtin_amdgcn_readfirstlane(tid >> 6);
  const int r0 = blockIdx.x * 2;

  __shared__ int s_idx[128];
  if (tid < 128) {
    int p = (int)out[OUT_IDX + (size_t)r0 * 64 + tid];
    s_idx[tid] = p;
    atomicAdd(&((int*)ws)[WS_HIST + p], 1);
  }
  __syncthreads();

  {
    float2* enc = (float2*)(out + OUT_ENC + (size_t)r0 * 64 * 512);
    const int o = tid * 2;
    for (int i = 0; i < 128; ++i) {
      int p = s_idx[i];
      float2 v;
      v.x = (o     == p) ? 1.f : 0.f;
      v.y = (o + 1 == p) ? 1.f : 0.f;
      enc[(size_t)i * 256 + tid] = v;
    }
  }

  float lsum = 0.f;
  {
    const int w  = tid & 63;
    const int cq = tid >> 6;
#pragma unroll 1
    for (int r2 = 0; r2 < 2; ++r2) {
      int rw = r0 + r2;
      int bb = rw >> 6, hh = rw & 63;
      size_t zb = (size_t)bb * 262144 + (size_t)hh * 64;
      int p = s_idx[r2 * 64 + w];
      const float* Ep = E + (size_t)p * 64;
#pragma unroll
      for (int c4 = 0; c4 < 64; c4 += 4) {
        int c = c4 + cq;
        float ev = Ep[c];
        float zv = z[zb + (size_t)c * 4096 + w];
        float d = ev - zv;
        lsum = fmaf(d, d, lsum);
        out[OUT_ZQ + zb + (size_t)c * 4096 + w] = ev;
      }
    }
  }
  for (int off = 32; off; off >>= 1) lsum += __shfl_down(lsum, off);
  __shared__ float s_l[4];
  if (lane == 0) s_l[waveu] = lsum;
  __syncthreads();
  if (tid == 0) ws[WS_LOSSP + blockIdx.x] = (s_l[0] + s_l[1]) + (s_l[2] + s_l[3]);
}

__global__ void vq_final(const float* __restrict__ ws, float* __restrict__ out) {
  int j = threadIdx.x; // 512
  const int* hist = (const int*)ws + WS_HIST;
  float p = (float)hist[j] * (1.f / 131072.f);
  float t = -p * logf(p + 1e-10f);
  float l = ws[WS_LOSSP + j] + ws[WS_LOSSP + j + 512];
  for (int off = 32; off; off >>= 1) {
    t += __shfl_down(t, off);
    l += __shfl_down(l, off);
  }
  __shared__ float st[8], sl[8];
  int wv = j >> 6, ln = j & 63;
  if (ln == 0) { st[wv] = t; sl[wv] = l; }
  __syncthreads();
  if (j == 0) {
    float e = 0.f, ls = 0.f;
#pragma unroll
    for (int i = 0; i < 8; ++i) { e += st[i]; ls += sl[i]; }
    out[OUT_PERP] = expf(e);
    out[0]        = ls * (1.25f / 8388608.0f);
  }
}

extern "C" void kernel_launch(void* const* d_in, const int* in_sizes, int n_in,
                              void* d_out, int out_size, void* d_ws, size_t ws_size,
                              hipStream_t stream) {
  const float* z = (const float*)d_in[0];
  const float* E = (const float*)d_in[1];
  float* out = (float*)d_out;
  float* ws  = (float*)d_ws;
  vq_setup<<<1, 512, 0, stream>>>(E, out, ws);
  vq_argmin_np<<<512, 256, 0, stream>>>(z, E, out + OUT_ENC, out);
  vq_outputs<<<1024, 256, 0, stream>>>(z, E, ws, out);
  vq_final<<<1, 512, 0, stream>>>(ws, out);
}

// Round 6
// 202.091 us; speedup vs baseline: 2.0271x; 2.0271x over previous
//
#include <hip/hip_runtime.h>
#include <math.h>

// z: [32,64,64,64] (B,C,H,W)  N = B*H*W = 131072 locations, C = 64
// E: [512,64]
// out (fp32 flat): loss(1) | z_q(8388608) | perp(1) | enc(67108864) | idx(131072)
#define OUT_ZQ   1LL
#define OUT_PERP 8388609LL
#define OUT_ENC  8388610LL
#define OUT_IDX  75497474LL

// ws (6 KB, proven-safe): [0..511] hist(int) | [512..1535] loss partials f32 (1024)
#define WS_HIST  0
#define WS_LOSSP 512

__global__ void vq_init(float* __restrict__ ws) {
  ((int*)ws)[WS_HIST + threadIdx.x] = 0;  // 512 threads
}

// Fused: np-replicated argmin + idx + hist + one-hot + z_q + loss partial.
// Block = 2 rows (128 locations); 4 waves = 2 rows x 2 j-halves.
// d_j = fl( fl(zsum + esum_j) - fl(2*mm_j) ); mm_j = sequential-k fp32 FMA chain;
// zsum/esum = numpy pairwise (8 accumulators). First-min: strict < ascending j,
// cross-half merge prefers lower half on ties.
__global__ __launch_bounds__(256, 4) void vq_fused(const float* __restrict__ z,
                                                   const float* __restrict__ E,
                                                   float* __restrict__ ws,
                                                   float* __restrict__ out) {
#pragma clang fp contract(off)
  const int tid  = threadIdx.x;
  const int lane = tid & 63;
  const int waveu = __builtin_amdgcn_readfirstlane(tid >> 6);
  const int rr    = waveu >> 1;          // block-local row
  const int jbase = (waveu & 1) * 256;   // j half
  const int r0  = blockIdx.x * 2;
  const int row = r0 + rr;
  const int b = row >> 6, h = row & 63;
  const size_t zbase = (size_t)b * 262144 + (size_t)h * 64;

  // per-block esum_j in LDS (numpy pairwise over fl(e^2); contract off)
  __shared__ float s_esum[512];
  for (int j = tid; j < 512; j += 256) {
    const float* e = E + j * 64;
    float q0 = e[0]*e[0], q1 = e[1]*e[1], q2 = e[2]*e[2], q3 = e[3]*e[3];
    float q4 = e[4]*e[4], q5 = e[5]*e[5], q6 = e[6]*e[6], q7 = e[7]*e[7];
#pragma unroll
    for (int i = 8; i < 64; i += 8) {
      q0 += e[i+0]*e[i+0]; q1 += e[i+1]*e[i+1];
      q2 += e[i+2]*e[i+2]; q3 += e[i+3]*e[i+3];
      q4 += e[i+4]*e[i+4]; q5 += e[i+5]*e[i+5];
      q6 += e[i+6]*e[i+6]; q7 += e[i+7]*e[i+7];
    }
    s_esum[j] = ((q0 + q1) + (q2 + q3)) + ((q4 + q5) + (q6 + q7));
  }

  // lane w holds its location's 64-dim vector
  float zf[64];
#pragma unroll
  for (int c = 0; c < 64; ++c)
    zf[c] = z[zbase + (size_t)c * 4096 + lane];

  // zsum: numpy pairwise over fl(z^2)
  float q0 = zf[0]*zf[0], q1 = zf[1]*zf[1], q2 = zf[2]*zf[2], q3 = zf[3]*zf[3];
  float q4 = zf[4]*zf[4], q5 = zf[5]*zf[5], q6 = zf[6]*zf[6], q7 = zf[7]*zf[7];
#pragma unroll
  for (int i = 8; i < 64; i += 8) {
    q0 += zf[i+0]*zf[i+0]; q1 += zf[i+1]*zf[i+1];
    q2 += zf[i+2]*zf[i+2]; q3 += zf[i+3]*zf[i+3];
    q4 += zf[i+4]*zf[i+4]; q5 += zf[i+5]*zf[i+5];
    q6 += zf[i+6]*zf[i+6]; q7 += zf[i+7]*zf[i+7];
  }
  const float zsum = ((q0 + q1) + (q2 + q3)) + ((q4 + q5) + (q6 + q7));
  __syncthreads();  // s_esum ready

  // main scan over this wave's j half
  float best = 1e30f; int bi = 0;
  const float* __restrict__ Ej = E + (size_t)jbase * 64;
  for (int jj = 0; jj < 256; jj += 4) {
    const float* __restrict__ e0 = Ej + jj * 64;  // wave-uniform -> s_load
    const float* __restrict__ e1 = e0 + 64;
    const float* __restrict__ e2 = e0 + 128;
    const float* __restrict__ e3 = e0 + 192;
    float a0 = 0.f, a1 = 0.f, a2 = 0.f, a3 = 0.f;
#pragma unroll
    for (int c = 0; c < 64; ++c) {   // sequential-k fused-FMA chain (BLAS-like)
      a0 = fmaf(zf[c], e0[c], a0);
      a1 = fmaf(zf[c], e1[c], a1);
      a2 = fmaf(zf[c], e2[c], a2);
      a3 = fmaf(zf[c], e3[c], a3);
    }
    const int j = jbase + jj;
    float d0 = (zsum + s_esum[j    ]) - 2.0f * a0;
    float d1 = (zsum + s_esum[j + 1]) - 2.0f * a1;
    float d2 = (zsum + s_esum[j + 2]) - 2.0f * a2;
    float d3 = (zsum + s_esum[j + 3]) - 2.0f * a3;
    if (d0 < best) { best = d0; bi = j;     }
    if (d1 < best) { best = d1; bi = j + 1; }
    if (d2 < best) { best = d2; bi = j + 2; }
    if (d3 < best) { best = d3; bi = j + 3; }
  }

  // merge j-halves (lower half wins ties -> global first-min)
  __shared__ float s_d[4][64];
  __shared__ int   s_i[4][64];
  __shared__ int   s_idx[128];
  s_d[waveu][lane] = best;
  s_i[waveu][lane] = bi;
  __syncthreads();
  if ((waveu & 1) == 0) {
    float dh = s_d[waveu + 1][lane];
    int   ih = s_i[waveu + 1][lane];
    if (dh < best) { best = dh; bi = ih; }
    s_idx[rr * 64 + lane] = bi;
    out[OUT_IDX + (size_t)row * 64 + lane] = (float)bi;
    atomicAdd(&((int*)ws)[WS_HIST + bi], 1);
  }
  __syncthreads();

  // one-hot: block's 128 locations, contiguous 256 KB (float2: 8B-aligned region)
  {
    float2* enc = (float2*)(out + OUT_ENC + (size_t)r0 * 64 * 512);
    const int o = tid * 2;
    for (int i = 0; i < 128; ++i) {
      int p = s_idx[i];
      float2 v;
      v.x = (o     == p) ? 1.f : 0.f;
      v.y = (o + 1 == p) ? 1.f : 0.f;
      enc[(size_t)i * 256 + tid] = v;
    }
  }

  // z_q + loss: waves 0,2 (zf already in registers for their row)
  float lsum = 0.f;
  if ((waveu & 1) == 0) {
    const int p = s_idx[rr * 64 + lane];
    const float* Ep = E + (size_t)p * 64;   // per-lane gather, L1/L2-hot
#pragma unroll
    for (int c = 0; c < 64; ++c) {
      float ev = Ep[c];
      float d = ev - zf[c];
      lsum = fmaf(d, d, lsum);
      out[OUT_ZQ + zbase + (size_t)c * 4096 + lane] = ev;  // 256B/instr coalesced
    }
  }
  for (int off = 32; off; off >>= 1) lsum += __shfl_down(lsum, off);
  __shared__ float s_l[4];
  if (lane == 0) s_l[waveu] = lsum;
  __syncthreads();
  if (tid == 0) ws[WS_LOSSP + blockIdx.x] = s_l[0] + s_l[2];
}

__global__ void vq_final(const float* __restrict__ ws, float* __restrict__ out) {
  int j = threadIdx.x; // 512
  const int* hist = (const int*)ws + WS_HIST;
  float p = (float)hist[j] * (1.f / 131072.f);
  float t = -p * logf(p + 1e-10f);
  float l = ws[WS_LOSSP + j] + ws[WS_LOSSP + j + 512];
  for (int off = 32; off; off >>= 1) {
    t += __shfl_down(t, off);
    l += __shfl_down(l, off);
  }
  __shared__ float st[8], sl[8];
  int wv = j >> 6, ln = j & 63;
  if (ln == 0) { st[wv] = t; sl[wv] = l; }
  __syncthreads();
  if (j == 0) {
    float e = 0.f, ls = 0.f;
#pragma unroll
    for (int i = 0; i < 8; ++i) { e += st[i]; ls += sl[i]; }
    out[OUT_PERP] = expf(e);
    out[0]        = ls * (1.25f / 8388608.0f);
  }
}

extern "C" void kernel_launch(void* const* d_in, const int* in_sizes, int n_in,
                              void* d_out, int out_size, void* d_ws, size_t ws_size,
                              hipStream_t stream) {
  const float* z = (const float*)d_in[0];
  const float* E = (const float*)d_in[1];
  float* out = (float*)d_out;
  float* ws  = (float*)d_ws;
  vq_init<<<1, 512, 0, stream>>>(ws);
  vq_fused<<<1024, 256, 0, stream>>>(z, E, ws, out);
  vq_final<<<1, 512, 0, stream>>>(ws, out);
}